// Round 2
// baseline (758.291 us; speedup 1.0000x reference)
//
#include <hip/hip_runtime.h>

typedef unsigned int u32;

#define N_NODES 30000
#define N_EDGES 600000
#define NBATCH  8
#define KVF     3
#define PER_B   3750          // N_NODES / NBATCH
#define NV      30024         // N_NODES + KVF*NBATCH
#define EV      780000        // N_EDGES + 2*KVF*N_NODES

// output element offsets (float32 elements)
#define O_V      0ULL
#define O_E      2281824ULL
#define O_TROT   168421824ULL
#define O_TTRANS 168692040ULL
#define O_TTSROT 168782112ULL
#define O_TTSTR  175802112ULL
#define O_BATCH  178142112ULL
#define O_EIDX   178172136ULL
#define O_CHAIN  179732136ULL
// total 179762160 f32 elements

// decouple() of a 3-vector -> 3 direction + 16 rbf features (f32)
__device__ __forceinline__ void decouple_store(float u0, float u1, float u2, float* dst) {
    float sq   = u0 * u0 + u1 * u1 + u2 * u2;
    float norm = sqrtf(sq + 1e-12f);
    float inv  = (norm < 1e-4f) ? 0.f : (1.f / (norm + 1e-6f));
    dst[0] = u0 * inv;
    dst[1] = u1 * inv;
    dst[2] = u2 * inv;
#pragma unroll
    for (int k = 0; k < 16; ++k) {
        float mu = 1.3333333333333333f * (float)k;   // linspace(0,20,16)
        float z  = (norm - mu) * 0.8f;               // sigma = 1.25
        dst[3 + k] = __expf(-z * z);
    }
}

__global__ __launch_bounds__(256) void node_kernel(
        const float* __restrict__ X, const int* __restrict__ batch_id,
        const int* __restrict__ chain, float* __restrict__ out,
        float* __restrict__ rec) {
    int i = blockIdx.x * blockDim.x + threadIdx.x;
    if (i >= NV) return;
    if (i < N_NODES) {
        const float* xi = X + (size_t)i * 12;
        float cax = xi[3], cay = xi[4], caz = xi[5];
        float nx = xi[0] - cax, ny = xi[1] - cay, nz = xi[2] - caz;
        float cx = xi[6] - cax, cy = xi[7] - cay, cz = xi[8] - caz;
        float h2   = cx * cx + cy * cy;
        float nrm  = sqrtf(1e-20f + h2);
        float s1 = -cy / nrm, c1 = cx / nrm;
        float nrm2 = sqrtf(1e-20f + h2 + cz * cz);
        float s2 = cz / nrm2, c2 = sqrtf(h2) / nrm2;
        // Rc = R2 @ R1
        float Rc00 = c2 * c1, Rc01 = -c2 * s1, Rc02 = s2;
        float Rc10 = s1,      Rc11 = c1;
        float Rc20 = -s2 * c1, Rc21 = s2 * s1, Rc22 = c2;
        float nr1 = Rc10 * nx + Rc11 * ny;
        float nr2 = Rc20 * nx + Rc21 * ny + Rc22 * nz;
        float nrm3 = sqrtf(1e-20f + nr1 * nr1 + nr2 * nr2);
        float sn = -nr2 / nrm3, cn = nr1 / nrm3;
        // M = Rn @ Rc ; output R = M^T
        float M00 = Rc00, M01 = Rc01, M02 = Rc02;
        float M10 = cn * Rc10 - sn * Rc20, M11 = cn * Rc11 - sn * Rc21, M12 = -sn * Rc22;
        float M20 = sn * Rc10 + cn * Rc20, M21 = sn * Rc11 + cn * Rc21, M22 = cn * Rc22;
        float r0 = M00, r1 = M10, r2 = M20;
        float r3 = M01, r4 = M11, r5 = M21;
        float r6 = M02, r7 = M12, r8 = M22;
        float* rw = rec + (size_t)i * 12;
        rw[0] = r0; rw[1] = r1; rw[2] = r2; rw[3] = r3; rw[4] = r4;
        rw[5] = r5; rw[6] = r6; rw[7] = r7; rw[8] = r8;
        rw[9] = cax; rw[10] = cay; rw[11] = caz;
        float* tr = out + O_TROT + (size_t)i * 9;
        tr[0] = r0; tr[1] = r1; tr[2] = r2;
        tr[3] = r3; tr[4] = r4; tr[5] = r5;
        tr[6] = r6; tr[7] = r7; tr[8] = r8;
        float* tt = out + O_TTRANS + (size_t)i * 3;
        tt[0] = cax; tt[1] = cay; tt[2] = caz;
        // V features: dX_loc[a] = M @ d[a]
        float* vp = out + O_V + (size_t)i * 76;
        bool zero_d = (i % PER_B) == 0;
#pragma unroll
        for (int a = 0; a < 4; ++a) {
            float d0, d1, d2;
            if (zero_d) {
                d0 = d1 = d2 = 0.f;
            } else {
                const float* pc = xi + a * 3;
                d0 = pc[0] - pc[-3]; d1 = pc[1] - pc[-2]; d2 = pc[2] - pc[-1];
            }
            float u0 = M00 * d0 + M01 * d1 + M02 * d2;
            float u1 = M10 * d0 + M11 * d1 + M12 * d2;
            float u2 = M20 * d0 + M21 * d1 + M22 * d2;
            decouple_store(u0, u1, u2, vp + a * 19);
        }
        out[O_BATCH + i] = (float)batch_id[i];
        out[O_CHAIN + i] = (float)chain[i];
    } else {
        int r = i - N_NODES;
        float kv = (float)(r >> 3);                // repeat(arange(K), B)
        float* vp = out + O_V + (size_t)i * 76;
#pragma unroll
        for (int j = 0; j < 38; ++j) {
            float freq = __expf((float)(2 * j) * (-9.210340371976184f / 76.f));
            float ang  = kv * freq;
            vp[j]      = cosf(ang);
            vp[38 + j] = sinf(ang);
        }
        float* tr = out + O_TROT + (size_t)i * 9;
#pragma unroll
        for (int j = 0; j < 9; ++j) tr[j] = (j == 0 || j == 4 || j == 8) ? 1.f : 0.f;
        float* tt = out + O_TTRANS + (size_t)i * 3;
        tt[0] = 0.f; tt[1] = 0.f; tt[2] = 0.f;
        out[O_BATCH + i] = (float)(r & 7);         // tile(arange(B), K)
        out[O_CHAIN + i] = 1001.f;
    }
}

__global__ __launch_bounds__(256) void edge_kernel(
        const float* __restrict__ X, const int* __restrict__ eidx,
        const int* __restrict__ node_idx, const float* __restrict__ rec,
        float* __restrict__ out) {
    __shared__ __align__(16) float sE[64 * 213];    // 54528 B
    __shared__ __align__(16) float sRot[64 * 9];    // 2304 B
    __shared__ __align__(16) float sTr[64 * 3];     // 768 B
    int tid  = threadIdx.x;
    int el   = tid & 63;
    int part = tid >> 6;
    int e = blockIdx.x * 64 + el;          // grid is exactly E/64 blocks
    int src = eidx[e];
    int dst = eidx[N_EDGES + e];
    float* se = sE + el * 213;

    if (part <= 1) {
        // diffE: loc[a] = R_src^T (pts[a] - t_src); atoms from X[src] (part0), X[dst] (part1)
        const float4* rs4 = (const float4*)(rec + (size_t)src * 12);
        float4 rA = rs4[0], rB = rs4[1], rC = rs4[2];
        float ts0 = rC.y, ts1 = rC.z, ts2 = rC.w;
        int nd = (part == 0) ? src : dst;
        const float4* xv = (const float4*)(X + (size_t)nd * 12);
        float4 x0 = xv[0], x1 = xv[1], x2 = xv[2];
        float px[4] = { x0.x, x0.w, x1.z, x2.y };
        float py[4] = { x0.y, x1.x, x1.w, x2.z };
        float pz[4] = { x0.z, x1.y, x2.x, x2.w };
        float* base = se + (part == 0 ? 0 : 76);
#pragma unroll
        for (int a = 0; a < 4; ++a) {
            float p0 = px[a] - ts0, p1 = py[a] - ts1, p2 = pz[a] - ts2;
            // Rs row-major: [rA.x rA.y rA.z; rA.w rB.x rB.y; rB.z rB.w rC.x]
            float u0 = rA.x * p0 + rA.w * p1 + rB.z * p2;
            float u1 = rA.y * p0 + rB.x * p1 + rB.w * p2;
            float u2 = rA.z * p0 + rB.y * p1 + rC.x * p2;
            decouple_store(u0, u1, u2, base + a * 19);
        }
    } else if (part == 2) {
        const float4* rs4 = (const float4*)(rec + (size_t)src * 12);
        float4 sA = rs4[0], sB = rs4[1], sC = rs4[2];
        const float4* rd4 = (const float4*)(rec + (size_t)dst * 12);
        float4 dA = rd4[0], dB = rd4[1], dC = rd4[2];
        float Rs[9] = { sA.x, sA.y, sA.z, sA.w, sB.x, sB.y, sB.z, sB.w, sC.x };
        float Rd[9] = { dA.x, dA.y, dA.z, dA.w, dB.x, dB.y, dB.z, dB.w, dC.x };
        float ts0 = sC.y, ts1 = sC.z, ts2 = sC.w;
        float td0 = dC.y, td1 = dC.z, td2 = dC.w;
        float* sr = sRot + el * 9;
#pragma unroll
        for (int ii = 0; ii < 3; ++ii) {
#pragma unroll
            for (int k = 0; k < 3; ++k) {
                // Rts[i][k] = sum_j Rd[j][i]*Rs[j][k]
                float q = Rd[ii] * Rs[k] + Rd[3 + ii] * Rs[3 + k] + Rd[6 + ii] * Rs[6 + k];
                sr[ii * 3 + k] = q;            // Tts_rot = Rts row-major
                se[152 + k * 3 + ii] = q;      // E_quant = Rts^T row-major
            }
        }
        float dt0 = ts0 - td0, dt1 = ts1 - td1, dt2 = ts2 - td2;
        float t0 = Rd[0] * dt0 + Rd[3] * dt1 + Rd[6] * dt2;
        float t1 = Rd[1] * dt0 + Rd[4] * dt1 + Rd[7] * dt2;
        float t2 = Rd[2] * dt0 + Rd[5] * dt1 + Rd[8] * dt2;
        float* st = sTr + el * 3;
        st[0] = t0; st[1] = t1; st[2] = t2;
        decouple_store(t0, t1, t2, se + 161);  // E_trans
    } else {
        // pos embedding of (src - dst), 16 features
        float dd = (float)(src - dst);
#pragma unroll
        for (int j = 0; j < 8; ++j) {
            float freq = __expf((float)(2 * j) * (-9.210340371976184f / 16.f));
            float ang  = dd * freq;
            se[180 + j] = cosf(ang);
            se[188 + j] = sinf(ang);
        }
        // E_bias: decouple of scalar b -> 1 + 16 features
        float b    = (float)(node_idx[src] - node_idx[dst]);
        float norm = sqrtf(b * b + 1e-12f);
        se[196] = (norm < 1e-4f) ? 0.f : (b / (norm + 1e-6f));
#pragma unroll
        for (int k = 0; k < 16; ++k) {
            float z = (norm - 1.3333333333333333f * (float)k) * 0.8f;
            se[197 + k] = __expf(-z * z);
        }
    }
    __syncthreads();
    // cooperative contiguous stores: 64*213 f32 = 3408 uint4; rot 144; trans 48
    const uint4* s4 = (const uint4*)sE;
    uint4* dE = (uint4*)(out + O_E) + (size_t)blockIdx.x * 3408;
    for (int i2 = tid; i2 < 3408; i2 += 256) dE[i2] = s4[i2];
    if (tid < 144) ((uint4*)(out + O_TTSROT))[(size_t)blockIdx.x * 144 + tid] = ((const uint4*)sRot)[tid];
    if (tid < 48)  ((uint4*)(out + O_TTSTR))[(size_t)blockIdx.x * 48 + tid]   = ((const uint4*)sTr)[tid];
}

// zero-fill virtual Efeat rows: 180000*213 f32 = 9,585,000 uint4
__global__ void fill_ve(float* __restrict__ out) {
    size_t i = (size_t)blockIdx.x * blockDim.x + threadIdx.x;
    if (i < 9585000ULL) {
        uint4 z; z.x = z.y = z.z = z.w = 0u;
        ((uint4*)(out + O_E + 600000ULL * 213ULL))[i] = z;
    }
}

// virtual Tts_rot rows = eye(3), Tts_trans rows = 0
__global__ void fill_tts(float* __restrict__ out) {
    int i = blockIdx.x * blockDim.x + threadIdx.x;
    if (i < 1620000) {   // 180000*9 f32
        int a = i % 9;
        out[O_TTSROT + 5400000ULL + i] = (a == 0 || a == 4 || a == 8) ? 1.f : 0.f;
    }
    if (i < 135000) {    // 180000*3 f32 = 135000 uint4
        uint4 z; z.x = z.y = z.z = z.w = 0u;
        ((uint4*)(out + O_TTSTR + 1800000ULL))[i] = z;
    }
}

__global__ void eidx_kernel(const int* __restrict__ ei, const int* __restrict__ batch_id,
                            float* __restrict__ out) {
    int i = blockIdx.x * blockDim.x + threadIdx.x;
    if (i >= 2 * EV) return;
    int row = i / EV;
    int col = i - row * EV;
    int v;
    if (col < N_EDGES) {
        v = ei[row * N_EDGES + col];
    } else {
        int j    = col - N_EDGES;          // [0, 2*K*N)
        int half = j / 90000;              // K*N = 90000
        int jj   = j - half * 90000;
        int k    = jj / N_NODES;
        int node = jj - k * N_NODES;
        bool takeSrc = (row == 0) ? (half == 0) : (half == 1);
        v = takeSrc ? (N_NODES + batch_id[node] + k * NBATCH) : node;
    }
    out[O_EIDX + i] = (float)v;
}

extern "C" void kernel_launch(void* const* d_in, const int* in_sizes, int n_in,
                              void* d_out, int out_size, void* d_ws, size_t ws_size,
                              hipStream_t stream) {
    const float* X        = (const float*)d_in[0];
    const int* node_idx   = (const int*)d_in[1];
    const int* eidx       = (const int*)d_in[2];
    const int* batch_id   = (const int*)d_in[3];
    const int* chain      = (const int*)d_in[4];
    float* out = (float*)d_out;
    float* rec = (float*)d_ws;   // 30000 * 12 floats = 1.44 MB

    node_kernel<<<(NV + 255) / 256, 256, 0, stream>>>(X, batch_id, chain, out, rec);
    edge_kernel<<<N_EDGES / 64, 256, 0, stream>>>(X, eidx, node_idx, rec, out);
    fill_ve<<<(9585000 + 255) / 256, 256, 0, stream>>>(out);
    fill_tts<<<(1620000 + 255) / 256, 256, 0, stream>>>(out);
    eidx_kernel<<<(2 * EV + 255) / 256, 256, 0, stream>>>(eidx, batch_id, out);
}